// Round 2
// baseline (440.895 us; speedup 1.0000x reference)
//
#include <hip/hip_runtime.h>
#include <math.h>

// VIN forward on MI355X — single fused kernel (prep folded in).
// Sizes: N=128, H=W=64, CH_I=2, CH_H=150, CH_Q=10, N_ACT=8, VInum=36.
//
// R1 -> R2 changes:
//  * prep (5x5 compose of conv0+conv_r) folded into vin_kernel, parallelized
//    750-way (was: separate 1-wave kernel costing ~110us of serial latency).
//  * v/r LDS row stride 66 -> 67: 4 rows/wave * stride 67 covers all 32 banks
//    at 2-way (free); stride 66 gave 4-way conflicts on every vwin read.
//  * inner VI math in packed fp32 (v_pk_fma_f32 via float2 ext-vector fma):
//    pixel pairs share the broadcast weight -> ~halves VALU issue.

typedef float v2f __attribute__((ext_vector_type(2)));

static __device__ __forceinline__ v2f splat2(float s) { v2f r; r.x = s; r.y = s; return r; }
static __device__ __forceinline__ v2f pkfma(float w, v2f v, v2f a) {
#if __has_builtin(__builtin_elementwise_fma)
    return __builtin_elementwise_fma(splat2(w), v, a);
#else
    v2f r; r.x = fmaf(w, v.x, a.x); r.y = fmaf(w, v.y, a.y); return r;
#endif
}

#define VROW 67
#define VSTR (66 * VROW)          // 4422 floats per v buffer

__global__ __launch_bounds__(1024)
void vin_kernel(const float* __restrict__ x,
                const int* __restrict__ S1,
                const int* __restrict__ S2,
                const int* __restrict__ VInum,
                const float* __restrict__ w0,
                const float* __restrict__ b0,
                const float* __restrict__ w_r,
                const float* __restrict__ w_q,
                const float* __restrict__ w_sw,
                const float* __restrict__ w_sw2,
                const float* __restrict__ w_dense,
                float* __restrict__ out) {
    const int b = blockIdx.x;
    const int t = threadIdx.x;

    __shared__ float pool[68 * 68 * 2];  // phase 1: xs[68][68][2]; phase 2: v[2][66][67]
    __shared__ float rs[66 * VROW];      // r with 1-halo of zeros, stride 67
    __shared__ float wtmp[840];          // W5 partials [0..749], B partials [750..839]
    __shared__ float wfin[60];           // W5[50], B[9], Btot
    __shared__ float qsel[10];

    // ---- zero LDS (halos must be 0) ----
    for (int i = t; i < 68 * 68 * 2; i += 1024) pool[i] = 0.f;
    for (int i = t; i < 66 * VROW; i += 1024) rs[i] = 0.f;
    __syncthreads();

    const int row = t >> 4;          // 0..63
    const int cb  = (t & 15) << 2;   // 0,4,...,60

    // ---- stage x into pool as xs[y+2][x+2][ci] (2-halo of zeros) ----
    {
        const float* xb = x + (size_t)b * 64 * 64 * 2;
        #pragma unroll
        for (int p = 0; p < 4; ++p) {
            int xx = cb + p;
            float2 v2 = *(const float2*)(xb + (row * 64 + xx) * 2);
            pool[((row + 2) * 68 + (xx + 2)) * 2 + 0] = v2.x;
            pool[((row + 2) * 68 + (xx + 2)) * 2 + 1] = v2.y;
        }
    }
    // ---- W5 compose partials: 50 entries x 15 channel-chunks ----
    if (t < 750) {
        int e2 = t / 15, pi = t - e2 * 15;
        int e = e2 >> 1, ci = e2 & 1;
        int ey = e / 5 - 2, ex = e % 5 - 2;
        int c0 = pi * 10;
        float s = 0.f;
        for (int dqy = -1; dqy <= 1; ++dqy)
            for (int dqx = -1; dqx <= 1; ++dqx) {
                int dsy = ey - dqy, dsx = ex - dqx;
                if (dsy < -1 || dsy > 1 || dsx < -1 || dsx > 1) continue;
                const float* wr = w_r + ((dqy + 1) * 3 + (dqx + 1)) * 150;
                const float* wp = w0 + (((dsy + 1) * 3 + (dsx + 1)) * 2 + ci) * 150;
                for (int c = c0; c < c0 + 10; ++c) s += wr[c] * wp[c];
            }
        wtmp[t] = s;
    } else if (t >= 768 && t < 858) {
        int j = t - 768;
        int d = j / 10, pi = j - d * 10, c0 = pi * 15;
        float s = 0.f;
        for (int c = c0; c < c0 + 15; ++c) s += w_r[d * 150 + c] * b0[c];
        wtmp[750 + j] = s;
    }
    __syncthreads();
    if (t < 50) {
        float s = 0.f;
        for (int i = 0; i < 15; ++i) s += wtmp[t * 15 + i];
        wfin[t] = s;
    } else if (t < 59) {
        int d = t - 50;
        float s = 0.f;
        for (int i = 0; i < 10; ++i) s += wtmp[750 + d * 10 + i];
        wfin[t] = s;
    } else if (t == 59) {
        float s = 0.f;
        for (int j = 0; j < 90; ++j) s += wtmp[750 + j];
        wfin[59] = s;
    }
    __syncthreads();

    // ---- r interior via composed 5x5 conv ----
    {
        float W5a[25], W5b[25];
        #pragma unroll
        for (int e = 0; e < 25; ++e) { W5a[e] = wfin[e * 2]; W5b[e] = wfin[e * 2 + 1]; }
        float Btot = wfin[59];
        #pragma unroll
        for (int p = 0; p < 4; ++p) {
            int xx = cb + p;
            float acc = Btot;
            #pragma unroll
            for (int ey = 0; ey < 5; ++ey)
                #pragma unroll
                for (int ex = 0; ex < 5; ++ex) {
                    const float* xp = &pool[((row + ey) * 68 + (xx + ex)) * 2];
                    acc += xp[0] * W5a[ey * 5 + ex] + xp[1] * W5b[ey * 5 + ex];
                }
            rs[(row + 1) * VROW + (xx + 1)] = acc;
        }
    }
    __syncthreads();

    // ---- border fix: subtract virtual-h contributions from 260 outside-q ----
    if (t < 780) {
        int qi = t / 3, ch = t - qi * 3;
        int qy, qx;
        if (qi < 66)       { qy = -1; qx = qi - 1; }
        else if (qi < 132) { qy = 64; qx = qi - 67; }
        else if (qi < 196) { qx = -1; qy = qi - 132; }
        else               { qx = 64; qy = qi - 196; }
        float sdq[9];
        #pragma unroll
        for (int d = 0; d < 9; ++d) sdq[d] = 0.f;
        int c0 = ch * 50;
        for (int c = c0; c < c0 + 50; ++c) {
            float hc = 0.f;
            #pragma unroll
            for (int ky = 0; ky < 3; ++ky)
                #pragma unroll
                for (int kx = 0; kx < 3; ++kx) {
                    const float* xp = &pool[((qy + ky + 1) * 68 + (qx + kx + 1)) * 2];
                    const float* wp = &w0[((ky * 3 + kx) * 2) * 150 + c];
                    hc += xp[0] * wp[0] + xp[1] * wp[150];
                }
            #pragma unroll
            for (int d = 0; d < 9; ++d) sdq[d] += w_r[d * 150 + c] * hc;
        }
        #pragma unroll
        for (int d = 0; d < 9; ++d) {
            int dy = d / 3 - 1, dx = d % 3 - 1;
            int py = qy - dy, px = qx - dx;
            if (py >= 0 && py < 64 && px >= 0 && px < 64) {
                float corr = sdq[d] + (ch == 0 ? wfin[50 + d] : 0.f);
                atomicAdd(&rs[(py + 1) * VROW + (px + 1)], -corr);
            }
        }
    }
    __syncthreads();

    // ---- reuse pool as v[2][66][67]: re-zero (halos!) ----
    for (int i = t; i < 2 * VSTR; i += 1024) pool[i] = 0.f;
    __syncthreads();

    const int K = VInum[0];

    // ---- Rsw precompute (loop-invariant r-part of w_sw conv) + first step (w_q) ----
    v2f Rsw[2][10];
    {
        float rwin[3][6];
        #pragma unroll
        for (int i = 0; i < 3; ++i) {
            const float* rp = &rs[(row + i) * VROW + cb];
            #pragma unroll
            for (int j = 0; j < 6; ++j) rwin[i][j] = rp[j];
        }
        #pragma unroll
        for (int pp = 0; pp < 2; ++pp) {
            v2f rv[9];
            #pragma unroll
            for (int d = 0; d < 9; ++d) {
                rv[d].x = rwin[d / 3][2 * pp + d % 3];
                rv[d].y = rwin[d / 3][2 * pp + 1 + d % 3];
            }
            v2f vmax = splat2(0.f);
            #pragma unroll
            for (int a = 0; a < 10; ++a) {
                v2f aR = splat2(0.f), aQ = splat2(0.f);
                #pragma unroll
                for (int d = 0; d < 9; ++d) {
                    aR = pkfma(w_sw[d * 20 + a], rv[d], aR);
                    aQ = pkfma(w_q[d * 20 + a],  rv[d], aQ);
                }
                Rsw[pp][a] = aR;
                if (a == 0) vmax = aQ;
                else { vmax.x = fmaxf(vmax.x, aQ.x); vmax.y = fmaxf(vmax.y, aQ.y); }
            }
            float* wb = &pool[0 * VSTR + (row + 1) * VROW + cb + 1 + 2 * pp];
            wb[0] = vmax.x; wb[1] = vmax.y;
        }
    }
    __syncthreads();

    // ---- K-1 shared-weight VI steps, double-buffered v, packed fp32 ----
    int cur = 0;
    for (int it = 0; it < K - 1; ++it) {
        const float* vb = &pool[cur * VSTR + row * VROW + cb];
        float vwin[3][6];
        #pragma unroll
        for (int i = 0; i < 3; ++i)
            #pragma unroll
            for (int j = 0; j < 6; ++j) vwin[i][j] = vb[i * VROW + j];
        int nxt = cur ^ 1;
        #pragma unroll
        for (int pp = 0; pp < 2; ++pp) {
            v2f vp[9];
            #pragma unroll
            for (int d = 0; d < 9; ++d) {
                vp[d].x = vwin[d / 3][2 * pp + d % 3];
                vp[d].y = vwin[d / 3][2 * pp + 1 + d % 3];
            }
            v2f vmax = splat2(0.f);
            #pragma unroll
            for (int a = 0; a < 10; ++a) {
                v2f acc = Rsw[pp][a];
                #pragma unroll
                for (int d = 0; d < 9; ++d)
                    acc = pkfma(w_sw[d * 20 + 10 + a], vp[d], acc);
                if (a == 0) vmax = acc;
                else { vmax.x = fmaxf(vmax.x, acc.x); vmax.y = fmaxf(vmax.y, acc.y); }
            }
            float* wb = &pool[nxt * VSTR + (row + 1) * VROW + cb + 1 + 2 * pp];
            wb[0] = vmax.x; wb[1] = vmax.y;
        }
        cur = nxt;
        __syncthreads();
    }

    // ---- final step with w_sw2: q -> global, gather (S1,S2) ----
    const int s1 = S1[b], s2 = S2[b];
    {
        float rwin[3][6], vwin[3][6];
        #pragma unroll
        for (int i = 0; i < 3; ++i) {
            const float* rp = &rs[(row + i) * VROW + cb];
            const float* vb = &pool[cur * VSTR + row * VROW + cb + i * VROW];
            #pragma unroll
            for (int j = 0; j < 6; ++j) { rwin[i][j] = rp[j]; vwin[i][j] = vb[j]; }
        }
        float qv[4][10];
        #pragma unroll
        for (int pp = 0; pp < 2; ++pp) {
            v2f rv[9], vp[9];
            #pragma unroll
            for (int d = 0; d < 9; ++d) {
                rv[d].x = rwin[d / 3][2 * pp + d % 3];
                rv[d].y = rwin[d / 3][2 * pp + 1 + d % 3];
                vp[d].x = vwin[d / 3][2 * pp + d % 3];
                vp[d].y = vwin[d / 3][2 * pp + 1 + d % 3];
            }
            #pragma unroll
            for (int a = 0; a < 10; ++a) {
                v2f acc = splat2(0.f);
                #pragma unroll
                for (int d = 0; d < 9; ++d) {
                    acc = pkfma(w_sw2[d * 20 + a],      rv[d], acc);
                    acc = pkfma(w_sw2[d * 20 + 10 + a], vp[d], acc);
                }
                qv[2 * pp][a] = acc.x;
                qv[2 * pp + 1][a] = acc.y;
            }
        }
        #pragma unroll
        for (int p = 0; p < 4; ++p) {
            float* qp = out + 2048 + ((size_t)((b * 64 + row) * 64 + cb + p)) * 10;
            #pragma unroll
            for (int h2 = 0; h2 < 5; ++h2)
                ((float2*)qp)[h2] = make_float2(qv[p][h2 * 2], qv[p][h2 * 2 + 1]);
        }
        #pragma unroll
        for (int p = 0; p < 4; ++p)
            if (row == s1 && s2 == cb + p) {
                #pragma unroll
                for (int a = 0; a < 10; ++a) qsel[a] = qv[p][a];
            }
    }
    __syncthreads();

    // ---- dense + softmax (thread 0), q_out (threads 0..9) ----
    if (t == 0) {
        float logits[8];
        float m = -1e30f;
        #pragma unroll
        for (int j = 0; j < 8; ++j) {
            float s = 0.f;
            #pragma unroll
            for (int a = 0; a < 10; ++a) s += qsel[a] * w_dense[a * 8 + j];
            logits[j] = s;
            m = fmaxf(m, s);
        }
        float sum = 0.f;
        float e[8];
        #pragma unroll
        for (int j = 0; j < 8; ++j) { e[j] = expf(logits[j] - m); sum += e[j]; }
        float inv = 1.f / sum;
        #pragma unroll
        for (int j = 0; j < 8; ++j) {
            out[b * 8 + j] = logits[j];
            out[1024 + b * 8 + j] = e[j] * inv;
        }
    }
    if (t < 10) out[5244928 + b * 10 + t] = qsel[t];
}

extern "C" void kernel_launch(void* const* d_in, const int* in_sizes, int n_in,
                              void* d_out, int out_size, void* d_ws, size_t ws_size,
                              hipStream_t stream) {
    const float* x      = (const float*)d_in[0];
    const int*   S1     = (const int*)d_in[1];
    const int*   S2     = (const int*)d_in[2];
    const int*   VInum  = (const int*)d_in[3];
    const float* w0     = (const float*)d_in[4];
    const float* b0     = (const float*)d_in[5];
    const float* w_r    = (const float*)d_in[6];
    const float* w_q    = (const float*)d_in[7];
    const float* w_sw   = (const float*)d_in[8];
    const float* w_sw2  = (const float*)d_in[9];
    const float* w_dense= (const float*)d_in[10];
    float* out = (float*)d_out;

    vin_kernel<<<128, 1024, 0, stream>>>(x, S1, S2, VInum, w0, b0, w_r, w_q,
                                         w_sw, w_sw2, w_dense, out);
}

// Round 3
// 382.893 us; speedup vs baseline: 1.1515x; 1.1515x over previous
//
#include <hip/hip_runtime.h>
#include <math.h>

// VIN forward on MI355X — single fused kernel.
// Sizes: N=128, H=W=64, CH_I=2, CH_H=150, CH_Q=10, N_ACT=8, VInum=36.
//
// R2 -> R3 changes:
//  * __launch_bounds__(1024, 4): 4 waves/EU -> 128-VGPR budget. R2's
//    VGPR_Count=44/52 vs a ~70+ live set (Rsw[4][10] alone is 40) meant the
//    backend was spilling/rematerializing the loop-invariant Rsw every
//    iteration -> scratch/L2 latency stalls (64% of loop wall). This is THE fix.
//  * Inner loop back to scalar fmaf (R1 form): packed v2f cost more VALU in
//    pair-building movs than it saved in FMAs (68us vs 55us issue time).
//  * x staged as two planes (xs0/xs1, stride 69): the old [y][x][2] layout
//    gave lanes 8-float strides -> 8-way bank conflicts on the 200-read 5x5
//    r-phase (~50K cy/WG, the bulk of SQ_LDS_BANK_CONFLICT).
//  * LDS un-unioned (xs | rs | vpool coexist, ~94 KB): drops one re-zero+barrier.

#define XROW 69
#define VROW 67
#define VSTR (66 * VROW)          // 4422 floats per v buffer

__global__ __launch_bounds__(1024, 4)
void vin_kernel(const float* __restrict__ x,
                const int* __restrict__ S1,
                const int* __restrict__ S2,
                const int* __restrict__ VInum,
                const float* __restrict__ w0,
                const float* __restrict__ b0,
                const float* __restrict__ w_r,
                const float* __restrict__ w_q,
                const float* __restrict__ w_sw,
                const float* __restrict__ w_sw2,
                const float* __restrict__ w_dense,
                float* __restrict__ out) {
    const int b = blockIdx.x;
    const int t = threadIdx.x;

    __shared__ float xs0[68 * XROW];     // x channel 0, [y+2][x+2], 2-halo of zeros
    __shared__ float xs1[68 * XROW];     // x channel 1
    __shared__ float rs[66 * VROW];      // r with 1-halo of zeros
    __shared__ float vpool[2 * VSTR];    // v double buffer, 1-halo of zeros
    __shared__ float wtmp[840];          // W5 partials [0..749], B partials [750..839]
    __shared__ float wfin[60];           // W5[50], B[9], Btot
    __shared__ float qsel[10];

    // ---- zero LDS (halos must be 0) ----
    for (int i = t; i < 68 * XROW; i += 1024) { xs0[i] = 0.f; xs1[i] = 0.f; }
    for (int i = t; i < 66 * VROW; i += 1024) rs[i] = 0.f;
    for (int i = t; i < 2 * VSTR; i += 1024) vpool[i] = 0.f;
    __syncthreads();

    const int row = t >> 4;          // 0..63
    const int cb  = (t & 15) << 2;   // 0,4,...,60

    // ---- stage x into split planes ----
    {
        const float* xb = x + (size_t)b * 64 * 64 * 2;
        #pragma unroll
        for (int p = 0; p < 4; ++p) {
            int xx = cb + p;
            float2 v2 = *(const float2*)(xb + (row * 64 + xx) * 2);
            xs0[(row + 2) * XROW + (xx + 2)] = v2.x;
            xs1[(row + 2) * XROW + (xx + 2)] = v2.y;
        }
    }
    // ---- W5 compose partials: 50 entries x 15 channel-chunks ----
    if (t < 750) {
        int e2 = t / 15, pi = t - e2 * 15;
        int e = e2 >> 1, ci = e2 & 1;
        int ey = e / 5 - 2, ex = e % 5 - 2;
        int c0 = pi * 10;
        float s = 0.f;
        for (int dqy = -1; dqy <= 1; ++dqy)
            for (int dqx = -1; dqx <= 1; ++dqx) {
                int dsy = ey - dqy, dsx = ex - dqx;
                if (dsy < -1 || dsy > 1 || dsx < -1 || dsx > 1) continue;
                const float* wr = w_r + ((dqy + 1) * 3 + (dqx + 1)) * 150;
                const float* wp = w0 + (((dsy + 1) * 3 + (dsx + 1)) * 2 + ci) * 150;
                for (int c = c0; c < c0 + 10; ++c) s += wr[c] * wp[c];
            }
        wtmp[t] = s;
    } else if (t >= 768 && t < 858) {
        int j = t - 768;
        int d = j / 10, pi = j - d * 10, c0 = pi * 15;
        float s = 0.f;
        for (int c = c0; c < c0 + 15; ++c) s += w_r[d * 150 + c] * b0[c];
        wtmp[750 + j] = s;
    }
    __syncthreads();
    if (t < 50) {
        float s = 0.f;
        for (int i = 0; i < 15; ++i) s += wtmp[t * 15 + i];
        wfin[t] = s;
    } else if (t < 59) {
        int d = t - 50;
        float s = 0.f;
        for (int i = 0; i < 10; ++i) s += wtmp[750 + d * 10 + i];
        wfin[t] = s;
    } else if (t == 59) {
        float s = 0.f;
        for (int j = 0; j < 90; ++j) s += wtmp[750 + j];
        wfin[59] = s;
    }
    __syncthreads();

    // ---- r interior via composed 5x5 conv (split planes, conflict-free) ----
    {
        float W5a[25], W5b[25];
        #pragma unroll
        for (int e = 0; e < 25; ++e) { W5a[e] = wfin[e * 2]; W5b[e] = wfin[e * 2 + 1]; }
        float Btot = wfin[59];
        #pragma unroll
        for (int p = 0; p < 4; ++p) {
            int xx = cb + p;
            float acc = Btot;
            #pragma unroll
            for (int ey = 0; ey < 5; ++ey)
                #pragma unroll
                for (int ex = 0; ex < 5; ++ex) {
                    int xi = (row + ey) * XROW + (xx + ex);
                    acc = fmaf(xs0[xi], W5a[ey * 5 + ex], acc);
                    acc = fmaf(xs1[xi], W5b[ey * 5 + ex], acc);
                }
            rs[(row + 1) * VROW + (xx + 1)] = acc;
        }
    }
    __syncthreads();

    // ---- border fix: subtract virtual-h contributions from 260 outside-q ----
    if (t < 780) {
        int qi = t / 3, ch = t - qi * 3;
        int qy, qx;
        if (qi < 66)       { qy = -1; qx = qi - 1; }
        else if (qi < 132) { qy = 64; qx = qi - 67; }
        else if (qi < 196) { qx = -1; qy = qi - 132; }
        else               { qx = 64; qy = qi - 196; }
        float sdq[9];
        #pragma unroll
        for (int d = 0; d < 9; ++d) sdq[d] = 0.f;
        int c0 = ch * 50;
        for (int c = c0; c < c0 + 50; ++c) {
            float hc = 0.f;
            #pragma unroll
            for (int ky = 0; ky < 3; ++ky)
                #pragma unroll
                for (int kx = 0; kx < 3; ++kx) {
                    int xi = (qy + ky + 1) * XROW + (qx + kx + 1);
                    const float* wp = &w0[((ky * 3 + kx) * 2) * 150 + c];
                    hc = fmaf(xs0[xi], wp[0], hc);
                    hc = fmaf(xs1[xi], wp[150], hc);
                }
            #pragma unroll
            for (int d = 0; d < 9; ++d) sdq[d] = fmaf(w_r[d * 150 + c], hc, sdq[d]);
        }
        #pragma unroll
        for (int d = 0; d < 9; ++d) {
            int dy = d / 3 - 1, dx = d % 3 - 1;
            int py = qy - dy, px = qx - dx;
            if (py >= 0 && py < 64 && px >= 0 && px < 64) {
                float corr = sdq[d] + (ch == 0 ? wfin[50 + d] : 0.f);
                atomicAdd(&rs[(py + 1) * VROW + (px + 1)], -corr);
            }
        }
    }
    __syncthreads();

    const int K = VInum[0];

    // ---- Rsw precompute (loop-invariant r-part of w_sw conv) + first step (w_q) ----
    float Rsw[4][10];
    {
        float rwin[3][6];
        #pragma unroll
        for (int i = 0; i < 3; ++i) {
            const float* rp = &rs[(row + i) * VROW + cb];
            #pragma unroll
            for (int j = 0; j < 6; ++j) rwin[i][j] = rp[j];
        }
        float vmax[4];
        #pragma unroll
        for (int a = 0; a < 10; ++a) {
            #pragma unroll
            for (int p = 0; p < 4; ++p) {
                float accR = 0.f, accQ = 0.f;
                #pragma unroll
                for (int d = 0; d < 9; ++d) {
                    float rv = rwin[d / 3][p + d % 3];
                    accR = fmaf(w_sw[d * 20 + a], rv, accR);
                    accQ = fmaf(w_q[d * 20 + a],  rv, accQ);
                }
                Rsw[p][a] = accR;
                vmax[p] = (a == 0) ? accQ : fmaxf(vmax[p], accQ);
            }
        }
        #pragma unroll
        for (int p = 0; p < 4; ++p)
            vpool[0 * VSTR + (row + 1) * VROW + (cb + p + 1)] = vmax[p];
    }
    __syncthreads();

    // ---- K-1 shared-weight VI steps, double-buffered v ----
    int cur = 0;
    for (int it = 0; it < K - 1; ++it) {
        const float* vb = &vpool[cur * VSTR + row * VROW + cb];
        float vwin[3][6];
        #pragma unroll
        for (int i = 0; i < 3; ++i)
            #pragma unroll
            for (int j = 0; j < 6; ++j) vwin[i][j] = vb[i * VROW + j];
        int nxt = cur ^ 1;
        float vmax[4];
        #pragma unroll
        for (int a = 0; a < 10; ++a) {
            #pragma unroll
            for (int p = 0; p < 4; ++p) {
                float acc = Rsw[p][a];
                #pragma unroll
                for (int d = 0; d < 9; ++d)
                    acc = fmaf(w_sw[d * 20 + 10 + a], vwin[d / 3][p + d % 3], acc);
                vmax[p] = (a == 0) ? acc : fmaxf(vmax[p], acc);
            }
        }
        #pragma unroll
        for (int p = 0; p < 4; ++p)
            vpool[nxt * VSTR + (row + 1) * VROW + (cb + p + 1)] = vmax[p];
        cur = nxt;
        __syncthreads();
    }

    // ---- final step with w_sw2: q -> global, gather (S1,S2) ----
    const int s1 = S1[b], s2 = S2[b];
    {
        float rwin[3][6], vwin[3][6];
        #pragma unroll
        for (int i = 0; i < 3; ++i) {
            const float* rp = &rs[(row + i) * VROW + cb];
            const float* vb = &vpool[cur * VSTR + (row + i) * VROW + cb];
            #pragma unroll
            for (int j = 0; j < 6; ++j) { rwin[i][j] = rp[j]; vwin[i][j] = vb[j]; }
        }
        float qv[4][10];
        #pragma unroll
        for (int a = 0; a < 10; ++a) {
            #pragma unroll
            for (int p = 0; p < 4; ++p) {
                float acc = 0.f;
                #pragma unroll
                for (int d = 0; d < 9; ++d) {
                    acc = fmaf(w_sw2[d * 20 + a],      rwin[d / 3][p + d % 3], acc);
                    acc = fmaf(w_sw2[d * 20 + 10 + a], vwin[d / 3][p + d % 3], acc);
                }
                qv[p][a] = acc;
            }
        }
        #pragma unroll
        for (int p = 0; p < 4; ++p) {
            float* qp = out + 2048 + ((size_t)((b * 64 + row) * 64 + cb + p)) * 10;
            #pragma unroll
            for (int h2 = 0; h2 < 5; ++h2)
                ((float2*)qp)[h2] = make_float2(qv[p][h2 * 2], qv[p][h2 * 2 + 1]);
        }
        #pragma unroll
        for (int p = 0; p < 4; ++p)
            if (row == s1 && s2 == cb + p) {
                #pragma unroll
                for (int a = 0; a < 10; ++a) qsel[a] = qv[p][a];
            }
    }
    __syncthreads();

    // ---- dense + softmax (thread 0), q_out (threads 0..9) ----
    if (t == 0) {
        float logits[8];
        float m = -1e30f;
        #pragma unroll
        for (int j = 0; j < 8; ++j) {
            float s = 0.f;
            #pragma unroll
            for (int a = 0; a < 10; ++a) s += qsel[a] * w_dense[a * 8 + j];
            logits[j] = s;
            m = fmaxf(m, s);
        }
        float sum = 0.f;
        float e[8];
        #pragma unroll
        for (int j = 0; j < 8; ++j) { e[j] = expf(logits[j] - m); sum += e[j]; }
        float inv = 1.f / sum;
        #pragma unroll
        for (int j = 0; j < 8; ++j) {
            out[b * 8 + j] = logits[j];
            out[1024 + b * 8 + j] = e[j] * inv;
        }
    }
    if (t < 10) out[5244928 + b * 10 + t] = qsel[t];
}

extern "C" void kernel_launch(void* const* d_in, const int* in_sizes, int n_in,
                              void* d_out, int out_size, void* d_ws, size_t ws_size,
                              hipStream_t stream) {
    const float* x      = (const float*)d_in[0];
    const int*   S1     = (const int*)d_in[1];
    const int*   S2     = (const int*)d_in[2];
    const int*   VInum  = (const int*)d_in[3];
    const float* w0     = (const float*)d_in[4];
    const float* b0     = (const float*)d_in[5];
    const float* w_r    = (const float*)d_in[6];
    const float* w_q    = (const float*)d_in[7];
    const float* w_sw   = (const float*)d_in[8];
    const float* w_sw2  = (const float*)d_in[9];
    const float* w_dense= (const float*)d_in[10];
    float* out = (float*)d_out;

    vin_kernel<<<128, 1024, 0, stream>>>(x, S1, S2, VInum, w0, b0, w_r, w_q,
                                         w_sw, w_sw2, w_dense, out);
}